// Round 3
// baseline (2707.493 us; speedup 1.0000x reference)
//
#include <hip/hip_runtime.h>
#include <hip/hip_bf16.h>
#include <stdint.h>

// CRF entity layer: B=64, T=512, H=768, K=32
// pot GEMM -> chunked parallel scans (L=8, 64 chunks/batch):
//   phaseA: per-chunk 32x32 maps: LSE (linear-space, normalized, f32) + Viterbi (max-plus)
//   phaseB: per-batch serial combine over 64 maps -> logZ, viterbi boundaries vb, last
//   phaseC: per-chunk recompute of viterbi alphas va from boundaries
//   bp_extract + backtrace (composition scan) as before.
//
// ws layout (bytes)                                  REQUIRES ws_size >= 44 MB
//   pot : 0         4MB (+4KB pad: staging overshoot)
//   va  : 4198400   4MB (+4KB pad)
//   bp  : 8396800   1MB
//   logZ: 9445376   256B
//   last: 9445632   256B
//   maps_lse: 9445888    16MB   (4096 chunks x 1024 f32)
//   s_lse   : 26223104   16KB
//   maps_vit: 26239488   16MB
//   vb      : 43016704   512KB  (64 b x 64 c x 32 f32)

#define TT 512
#define KK 32
#define HH 768
#define NB 64

#define WS_POT  0
#define WS_VA   4198400
#define WS_BP   8396800
#define WS_LOGZ 9445376
#define WS_LAST 9445632
#define WS_MLSE 9445888
#define WS_SLSE 26223104
#define WS_MVIT 26239488
#define WS_VB   43016704

// replicate a half-wave's 32 values into registers, XOR order: r[p] = val_of_lane(k^p)
__device__ __forceinline__ void repl32(float own, float* r) {
  r[0] = own;
#pragma unroll
  for (int m = 0; m < 5; ++m) {
#pragma unroll
    for (int p = 0; p < 32; ++p) {
      if (p < (1 << m)) r[(1 << m) + p] = __shfl_xor(r[p], 1 << m, 32);
    }
  }
}

// ---------------------------------------------------------------- GEMM ------
__global__ __launch_bounds__(256) void gemm_pot(const float* __restrict__ x,
                                                const float* __restrict__ W,
                                                const float* __restrict__ bias,
                                                float* __restrict__ pot) {
  __shared__ float4 xs4[64][16];
  __shared__ float4 wt4[32][16];
  const int tid = threadIdx.x;
  const int row0 = blockIdx.x * 64;
  const int cg = tid & 15;
  const int rg = tid >> 4;
  const int c0 = cg * 2;
  float acc[4][2] = {{0.f, 0.f}, {0.f, 0.f}, {0.f, 0.f}, {0.f, 0.f}};

  for (int h0 = 0; h0 < HH; h0 += 64) {
#pragma unroll
    for (int p = 0; p < 4; ++p) {
      const int fi = tid + p * 256;
      const int r = fi >> 4, s = fi & 15;
      const float4 v = *(const float4*)(&x[(size_t)(row0 + r) * HH + h0 + s * 4]);
      xs4[r][s ^ ((r >> 2) & 3)] = v;
    }
    {
      const int c = tid & 31;
      const int hb = (tid >> 5) * 8;
      float* wf = (float*)(&wt4[0][0]);
#pragma unroll
      for (int i2 = 0; i2 < 8; ++i2) {
        const int hh = hb + i2;
        const int slot = (hh >> 2) ^ ((c >> 1) & 15);
        wf[c * 64 + slot * 4 + (hh & 3)] = W[(size_t)(h0 + hh) * KK + c];
      }
    }
    __syncthreads();
#pragma unroll
    for (int s = 0; s < 16; ++s) {
      float4 xv[4];
#pragma unroll
      for (int i = 0; i < 4; ++i) xv[i] = xs4[rg * 4 + i][s ^ (rg & 3)];
      const float4 wv0 = wt4[c0][s ^ cg];
      const float4 wv1 = wt4[c0 + 1][s ^ cg];
#pragma unroll
      for (int i = 0; i < 4; ++i) {
        acc[i][0] += xv[i].x * wv0.x + xv[i].y * wv0.y + xv[i].z * wv0.z + xv[i].w * wv0.w;
        acc[i][1] += xv[i].x * wv1.x + xv[i].y * wv1.y + xv[i].z * wv1.z + xv[i].w * wv1.w;
      }
    }
    __syncthreads();
  }
#pragma unroll
  for (int i = 0; i < 4; ++i) {
    const int row = row0 + rg * 4 + i;
    float2 o = make_float2(acc[i][0] + bias[c0], acc[i][1] + bias[c0 + 1]);
    *(float2*)(&pot[(size_t)row * KK + c0]) = o;
  }
}

// --------------------------------------------------------------- phase A ----
// grid 1024 x 256: blocks [0,512) LSE maps, [512,1024) Viterbi maps.
// block = 8 consecutive chunks (same batch); wave handles 2 chunks (row i per lane).
__global__ __launch_bounds__(256) void phaseA(const float* __restrict__ pot,
                                              const int* __restrict__ lens,
                                              const float* __restrict__ trans,
                                              float* __restrict__ maps_lse,
                                              float* __restrict__ scale_lse,
                                              float* __restrict__ maps_vit) {
  __shared__ float tr_s[1024];
  __shared__ float pr_s[2048];   // 64 t-rows x 32 (exp()'d for LSE)
  const int tid = threadIdx.x;
  const bool is_lse = (blockIdx.x < 512);
  const int blk = is_lse ? blockIdx.x : blockIdx.x - 512;
  const int id0 = blk * 8;
  const int b = id0 >> 6;
  const int c0 = id0 & 63;

#pragma unroll
  for (int q = 0; q < 4; ++q) {
    const float v = trans[tid + q * 256];
    tr_s[tid + q * 256] = is_lse ? expf(v) : v;
  }
  {
    const float4* src = (const float4*)(pot + ((size_t)b * TT + 8 * c0 + 1) * KK);
#pragma unroll
    for (int q = 0; q < 2; ++q) {
      float4 v = src[tid + q * 256];
      if (is_lse) { v.x = expf(v.x); v.y = expf(v.y); v.z = expf(v.z); v.w = expf(v.w); }
      ((float4*)pr_s)[tid + q * 256] = v;
    }
  }
  __syncthreads();

  const int lane = tid & 63;
  const int i = lane & 31;
  const int jloc = (tid >> 6) * 2 + (lane >> 5);
  const int id = id0 + jloc;
  const int c = c0 + jloc;
  const int len = lens[b];
  const int t0 = 8 * c + 1;
  const int t1 = min(8 * c + 8, len - 1);

  float M[32];
  if (is_lse) {
    if (t0 <= t1) {
#pragma unroll
      for (int k4 = 0; k4 < 8; ++k4) {
        const float4 e = ((const float4*)(tr_s + i * 32))[k4];
        const float4 p = ((const float4*)(pr_s + jloc * 256))[k4];
        M[4 * k4 + 0] = e.x * p.x; M[4 * k4 + 1] = e.y * p.y;
        M[4 * k4 + 2] = e.z * p.z; M[4 * k4 + 3] = e.w * p.w;
      }
    } else {
#pragma unroll
      for (int k = 0; k < 32; ++k) M[k] = (k == i) ? 1.f : 0.f;
    }
#pragma unroll 1
    for (int s = 1; s < 8; ++s) {
      const int t = t0 + s;
      if (__all(t > t1)) break;
      float acc[32];
#pragma unroll
      for (int k = 0; k < 32; ++k) acc[k] = 0.f;
#pragma unroll
      for (int jj = 0; jj < 32; ++jj) {
        const float mj = M[jj];
#pragma unroll
        for (int k4 = 0; k4 < 8; ++k4) {
          const float4 e = ((const float4*)(tr_s + jj * 32))[k4];
          acc[4 * k4 + 0] += mj * e.x; acc[4 * k4 + 1] += mj * e.y;
          acc[4 * k4 + 2] += mj * e.z; acc[4 * k4 + 3] += mj * e.w;
        }
      }
      const bool act = (t <= t1);
#pragma unroll
      for (int k4 = 0; k4 < 8; ++k4) {
        const float4 p = ((const float4*)(pr_s + (jloc * 8 + s) * 32))[k4];
        M[4 * k4 + 0] = act ? acc[4 * k4 + 0] * p.x : M[4 * k4 + 0];
        M[4 * k4 + 1] = act ? acc[4 * k4 + 1] * p.y : M[4 * k4 + 1];
        M[4 * k4 + 2] = act ? acc[4 * k4 + 2] * p.z : M[4 * k4 + 2];
        M[4 * k4 + 3] = act ? acc[4 * k4 + 3] * p.w : M[4 * k4 + 3];
      }
    }
    float mx = M[0];
#pragma unroll
    for (int k = 1; k < 32; ++k) mx = fmaxf(mx, M[k]);
#pragma unroll
    for (int mm = 16; mm >= 1; mm >>= 1) mx = fmaxf(mx, __shfl_xor(mx, mm, 32));
    const float inv = 1.0f / mx;
    float4* dst = (float4*)(maps_lse + (size_t)id * 1024 + i * 32);
#pragma unroll
    for (int k4 = 0; k4 < 8; ++k4)
      dst[k4] = make_float4(M[4 * k4] * inv, M[4 * k4 + 1] * inv, M[4 * k4 + 2] * inv, M[4 * k4 + 3] * inv);
    if (i == 0) scale_lse[id] = logf(mx);
  } else {
    if (t0 <= t1) {
#pragma unroll
      for (int k4 = 0; k4 < 8; ++k4) {
        const float4 e = ((const float4*)(tr_s + i * 32))[k4];
        const float4 p = ((const float4*)(pr_s + jloc * 256))[k4];
        M[4 * k4 + 0] = e.x + p.x; M[4 * k4 + 1] = e.y + p.y;
        M[4 * k4 + 2] = e.z + p.z; M[4 * k4 + 3] = e.w + p.w;
      }
    } else {
#pragma unroll
      for (int k = 0; k < 32; ++k) M[k] = (k == i) ? 0.f : -1e30f;
    }
#pragma unroll 1
    for (int s = 1; s < 8; ++s) {
      const int t = t0 + s;
      if (__all(t > t1)) break;
      float acc[32];
#pragma unroll
      for (int k = 0; k < 32; ++k) acc[k] = -1e30f;
#pragma unroll
      for (int jj = 0; jj < 32; ++jj) {
        const float mj = M[jj];
#pragma unroll
        for (int k4 = 0; k4 < 8; ++k4) {
          const float4 e = ((const float4*)(tr_s + jj * 32))[k4];
          acc[4 * k4 + 0] = fmaxf(acc[4 * k4 + 0], mj + e.x);
          acc[4 * k4 + 1] = fmaxf(acc[4 * k4 + 1], mj + e.y);
          acc[4 * k4 + 2] = fmaxf(acc[4 * k4 + 2], mj + e.z);
          acc[4 * k4 + 3] = fmaxf(acc[4 * k4 + 3], mj + e.w);
        }
      }
      const bool act = (t <= t1);
#pragma unroll
      for (int k4 = 0; k4 < 8; ++k4) {
        const float4 p = ((const float4*)(pr_s + (jloc * 8 + s) * 32))[k4];
        M[4 * k4 + 0] = act ? acc[4 * k4 + 0] + p.x : M[4 * k4 + 0];
        M[4 * k4 + 1] = act ? acc[4 * k4 + 1] + p.y : M[4 * k4 + 1];
        M[4 * k4 + 2] = act ? acc[4 * k4 + 2] + p.z : M[4 * k4 + 2];
        M[4 * k4 + 3] = act ? acc[4 * k4 + 3] + p.w : M[4 * k4 + 3];
      }
    }
    float4* dst = (float4*)(maps_vit + (size_t)id * 1024 + i * 32);
#pragma unroll
    for (int k4 = 0; k4 < 8; ++k4)
      dst[k4] = make_float4(M[4 * k4], M[4 * k4 + 1], M[4 * k4 + 2], M[4 * k4 + 3]);
  }
}

// --------------------------------------------------------------- phase B ----
// grid 128 x 256: blocks [0,64) LSE (logZ), [64,128) Viterbi (vb boundaries + last).
// wave0/lanes0-31 do the serial combine; other waves double-buffer stage maps.
__global__ __launch_bounds__(256) void phaseB(const float* __restrict__ pot,
                                              const float* __restrict__ maps_lse,
                                              const float* __restrict__ scale_lse,
                                              const float* __restrict__ maps_vit,
                                              float* __restrict__ vb,
                                              float* __restrict__ logZ,
                                              int* __restrict__ last) {
  __shared__ float mbuf[2][8 * 1024];   // 64KB: 2 rounds x 8 maps
  const int tid = threadIdx.x;
  const bool is_lse = (blockIdx.x < 64);
  const int b = is_lse ? blockIdx.x : blockIdx.x - 64;
  const float* maps = is_lse ? maps_lse : maps_vit;

  {
    const float4* src = (const float4*)(maps + (size_t)b * 65536);
    for (int q = tid; q < 2048; q += 256) ((float4*)mbuf[0])[q] = src[q];
  }
  __syncthreads();

  const int k = tid;
  float areg[32];
  float aown = 0.f, alog = 0.f;
  if (tid < 32) {
    const float a0 = pot[(size_t)b * (TT * KK) + k];
    if (is_lse) {
      float m0 = a0;
#pragma unroll
      for (int mm = 16; mm >= 1; mm >>= 1) m0 = fmaxf(m0, __shfl_xor(m0, mm, 32));
      aown = expf(a0 - m0);
      alog = m0;
    } else {
      aown = a0;
    }
    repl32(aown, areg);
  }

  for (int r = 0; r < 8; ++r) {
    if (r < 7 && tid >= 64) {
      const float4* src = (const float4*)(maps + (size_t)b * 65536 + (size_t)(r + 1) * 8192);
      float4* dst = (float4*)mbuf[(r + 1) & 1];
      for (int q = tid - 64; q < 2048; q += 192) dst[q] = src[q];
    }
    if (tid < 32) {
      const float* mb0 = mbuf[r & 1];
#pragma unroll 1
      for (int m2 = 0; m2 < 8; ++m2) {
        const float* mb = mb0 + m2 * 1024;
        const int cc = r * 8 + m2;
        if (is_lse) {
          float s0 = 0.f, s1 = 0.f, s2 = 0.f, s3 = 0.f;
#pragma unroll
          for (int p = 0; p < 32; ++p) {
            const float v = mb[((k ^ p) << 5) + k];
            if ((p & 3) == 0) s0 += areg[p] * v;
            else if ((p & 3) == 1) s1 += areg[p] * v;
            else if ((p & 3) == 2) s2 += areg[p] * v;
            else s3 += areg[p] * v;
          }
          const float nown = (s0 + s1) + (s2 + s3);
          float mx = nown;
#pragma unroll
          for (int mm = 16; mm >= 1; mm >>= 1) mx = fmaxf(mx, __shfl_xor(mx, mm, 32));
          alog += logf(mx) + scale_lse[b * 64 + cc];
          aown = nown / mx;
          repl32(aown, areg);
        } else {
          vb[((size_t)b * 64 + cc) * 32 + k] = aown;
          float nmax = -1e30f;
#pragma unroll
          for (int p = 0; p < 32; ++p)
            nmax = fmaxf(nmax, areg[p] + mb[((k ^ p) << 5) + k]);
          aown = nmax;
          repl32(aown, areg);
        }
      }
    }
    __syncthreads();
  }
  if (tid < 32) {
    if (is_lse) {
      float ssum = aown;
#pragma unroll
      for (int mm = 16; mm >= 1; mm >>= 1) ssum += __shfl_xor(ssum, mm, 32);
      if (k == 0) logZ[b] = alog + logf(ssum);
    } else {
      float v = aown;
      int idx = k;
#pragma unroll
      for (int mm = 16; mm >= 1; mm >>= 1) {
        const float vo = __shfl_xor(v, mm, 32);
        const int io = __shfl_xor(idx, mm, 32);
        if (vo > v || (vo == v && io < idx)) { v = vo; idx = io; }
      }
      if (k == 0) last[b] = idx;
    }
  }
}

// --------------------------------------------------------------- phase C ----
// grid 512 x 256: 8 chunks/block; half-wave per chunk recomputes 7 steps -> va.
__global__ __launch_bounds__(256) void phaseC(const float* __restrict__ pot,
                                              const int* __restrict__ lens,
                                              const float* __restrict__ trans,
                                              const float* __restrict__ vb,
                                              float* __restrict__ va) {
  __shared__ float tr_s[1024];
  const int tid = threadIdx.x;
#pragma unroll
  for (int q = 0; q < 4; ++q) tr_s[tid + q * 256] = trans[tid + q * 256];
  __syncthreads();
  const int lane = tid & 63;
  const int k = lane & 31;
  const int jloc = (tid >> 6) * 2 + (lane >> 5);
  const int id = blockIdx.x * 8 + jloc;
  const int b = id >> 6, c = id & 63;
  const int len = lens[b];
  float areg[32];
  float aown = vb[(size_t)id * 32 + k];
  repl32(aown, areg);
  float* vap = va + (size_t)b * (TT * KK);
  const float* pp = pot + (size_t)b * (TT * KK);
  vap[(8 * c) * 32 + k] = aown;
#pragma unroll 1
  for (int s = 1; s < 8; ++s) {
    const int t = 8 * c + s;
    if (__all(t >= len)) break;
    float nmax = -1e30f;
#pragma unroll
    for (int p = 0; p < 32; ++p) nmax = fmaxf(nmax, areg[p] + tr_s[((k ^ p) << 5) + k]);
    const float nv = nmax + pp[t * 32 + k];
    aown = (t < len) ? nv : aown;
    repl32(aown, areg);
    vap[t * 32 + k] = aown;
  }
}

// ----------------------------------------------------------- bp extract -----
__global__ __launch_bounds__(256) void bp_extract(const float* __restrict__ va,
                                                  const float* __restrict__ trans,
                                                  unsigned char* __restrict__ bp) {
  const int b = blockIdx.x >> 3;
  const int tbase = (blockIdx.x & 7) * 64;
  const int k = threadIdx.x & 31;
  const int ts = threadIdx.x >> 5;
  float tr[32];
#pragma unroll
  for (int j = 0; j < 32; ++j) tr[j] = trans[j * KK + k];
#pragma unroll
  for (int it = 0; it < 8; ++it) {
    const int t = tbase + it * 8 + ts;
    if (t < 1) continue;
    const float* row = va + ((size_t)b * TT + (t - 1)) * KK;
    float best = row[0] + tr[0];
    int bi = 0;
#pragma unroll
    for (int j = 1; j < 32; ++j) {
      const float s = row[j] + tr[j];
      if (s > best) { best = s; bi = j; }
    }
    bp[((size_t)b * TT + t) * KK + k] = (unsigned char)bi;
  }
}

// ------------------------------------------------------------- backtrace ----
__global__ __launch_bounds__(256) void backtrace_kernel(
    const unsigned char* __restrict__ bp, const int* __restrict__ lens,
    const int* __restrict__ last, const float* __restrict__ pot,
    const int* __restrict__ y, const float* __restrict__ trans,
    const float* __restrict__ logZ, float* __restrict__ out) {
  __shared__ unsigned char Ls[32736];
  __shared__ unsigned char sA[512], sB[512];
  __shared__ float red[256];
  const int b = blockIdx.x, tid = threadIdx.x;
  const int len = lens[b];

  for (int i = tid; i < TT * KK; i += 256) {
    const int t = i >> 5, k = i & 31;
    Ls[i] = (t >= 1 && t < len) ? bp[((size_t)b * TT + t) * KK + k] : (unsigned char)k;
  }
  __syncthreads();

  int off_prev = 0, cnt = 512;
  for (int l = 1; l <= 9; ++l) {
    const int off = 32 * (1024 - (1024 >> l));
    const int n = cnt >> 1;
    for (int i = tid; i < n * 32; i += 256) {
      const int m = i >> 5, k = i & 31;
      const int inner = Ls[off_prev + (2 * m + 1) * 32 + k];
      Ls[off + i] = Ls[off_prev + (2 * m) * 32 + inner];
    }
    __syncthreads();
    off_prev = off;
    cnt = n;
  }

  if (tid == 0) sA[0] = (unsigned char)last[b];
  __syncthreads();

  unsigned char* cur = sA;
  unsigned char* nxt = sB;
  int c2 = 1;
  for (int l = 9; l >= 1; --l) {
    const int offm = 32 * (1024 - (1024 >> (l - 1)));
    for (int i = tid; i < c2; i += 256) {
      const unsigned char s = cur[i];
      nxt[2 * i + 1] = s;
      nxt[2 * i] = Ls[offm + (2 * i + 1) * 32 + s];
    }
    __syncthreads();
    unsigned char* tmp = cur; cur = nxt; nxt = tmp;
    c2 <<= 1;
  }

  for (int t = tid; t < TT; t += 256)
    out[NB + (size_t)b * TT + t] = (t < len) ? (float)cur[t] : 0.f;

  float acc = 0.f;
  for (int t = tid; t < TT; t += 256) {
    const int yt = y[b * TT + t];
    if (t < len) acc += pot[((size_t)b * TT + t) * KK + yt];
    if (t < len - 1) acc += trans[yt * KK + y[b * TT + t + 1]];
  }
  red[tid] = acc;
  __syncthreads();
  for (int s = 128; s >= 1; s >>= 1) {
    if (tid < s) red[tid] += red[tid + s];
    __syncthreads();
  }
  if (tid == 0) out[b] = red[0] - logZ[b];
}

// ------------------------------------------------------------------ launch --
extern "C" void kernel_launch(void* const* d_in, const int* in_sizes, int n_in,
                              void* d_out, int out_size, void* d_ws, size_t ws_size,
                              hipStream_t stream) {
  const float* x = (const float*)d_in[0];
  const int* y = (const int*)d_in[1];
  const int* lens = (const int*)d_in[2];
  const float* W = (const float*)d_in[3];
  const float* bias = (const float*)d_in[4];
  const float* trans = (const float*)d_in[5];
  float* out = (float*)d_out;
  char* ws = (char*)d_ws;
  float* pot = (float*)(ws + WS_POT);
  float* va = (float*)(ws + WS_VA);
  unsigned char* bp = (unsigned char*)(ws + WS_BP);
  float* logZ = (float*)(ws + WS_LOGZ);
  int* last = (int*)(ws + WS_LAST);
  float* maps_lse = (float*)(ws + WS_MLSE);
  float* s_lse = (float*)(ws + WS_SLSE);
  float* maps_vit = (float*)(ws + WS_MVIT);
  float* vb = (float*)(ws + WS_VB);

  gemm_pot<<<512, 256, 0, stream>>>(x, W, bias, pot);
  phaseA<<<1024, 256, 0, stream>>>(pot, lens, trans, maps_lse, s_lse, maps_vit);
  phaseB<<<128, 256, 0, stream>>>(pot, maps_lse, s_lse, maps_vit, vb, logZ, last);
  phaseC<<<512, 256, 0, stream>>>(pot, lens, trans, vb, va);
  bp_extract<<<512, 256, 0, stream>>>(va, trans, bp);
  backtrace_kernel<<<64, 256, 0, stream>>>(bp, lens, last, pot, y, trans, logZ, out);
}

// Round 4
// 204.082 us; speedup vs baseline: 13.2667x; 13.2667x over previous
//
#include <hip/hip_runtime.h>
#include <hip/hip_bf16.h>
#include <stdint.h>

// CRF entity layer: B=64, T=512, H=768, K=32
//   1) gemm_pot: pot[b][t][k] = x[b,t,:]·W[:,k] + b[k]
//   2) scan2:    blocks [0,64)  : linear-space LSE forward -> logZ[b]
//                blocks [64,128): Viterbi max-plus forward -> va, last[b]
//      1 batch/wave; j-split across wave halves; repl16 shuffle tree; no LDS.
//   3) bp_extract: bp[b][t][k] = argmax_j(va[t-1][j]+trans[j][k])
//   4) backtrace: log-depth composition scan -> preds; + seq score -> ll
//
// ws layout (bytes):
//   pot : 0         4MB (+4KB pad: prefetch overshoot to t<=543)
//   va  : 4198400   4MB (+4KB pad)
//   bp  : 8396800   1MB
//   logZ: 9445376   256B
//   last: 9445632   256B

#define TT 512
#define KK 32
#define HH 768
#define NB 64

#define WS_POT 0
#define WS_VA  4198400
#define WS_BP  8396800
#define WS_LOGZ 9445376
#define WS_LAST 9445632

__device__ __forceinline__ float wmax32(float v) {
#pragma unroll
  for (int m = 16; m >= 1; m >>= 1) v = fmaxf(v, __shfl_xor(v, m, 32));
  return v;
}
__device__ __forceinline__ float wsum32(float v) {
#pragma unroll
  for (int m = 16; m >= 1; m >>= 1) v += __shfl_xor(v, m, 32);
  return v;
}

// ---------------------------------------------------------------- GEMM ------
__global__ __launch_bounds__(256) void gemm_pot(const float* __restrict__ x,
                                                const float* __restrict__ W,
                                                const float* __restrict__ bias,
                                                float* __restrict__ pot) {
  __shared__ float4 xs4[64][16];
  __shared__ float4 wt4[32][16];
  const int tid = threadIdx.x;
  const int row0 = blockIdx.x * 64;
  const int cg = tid & 15;
  const int rg = tid >> 4;
  const int c0 = cg * 2;
  float acc[4][2] = {{0.f, 0.f}, {0.f, 0.f}, {0.f, 0.f}, {0.f, 0.f}};

  for (int h0 = 0; h0 < HH; h0 += 64) {
#pragma unroll
    for (int p = 0; p < 4; ++p) {
      const int fi = tid + p * 256;
      const int r = fi >> 4, s = fi & 15;
      const float4 v = *(const float4*)(&x[(size_t)(row0 + r) * HH + h0 + s * 4]);
      xs4[r][s ^ ((r >> 2) & 3)] = v;
    }
    {
      const int c = tid & 31;
      const int hb = (tid >> 5) * 8;
      float* wf = (float*)(&wt4[0][0]);
#pragma unroll
      for (int i2 = 0; i2 < 8; ++i2) {
        const int hh = hb + i2;
        const int slot = (hh >> 2) ^ ((c >> 1) & 15);
        wf[c * 64 + slot * 4 + (hh & 3)] = W[(size_t)(h0 + hh) * KK + c];
      }
    }
    __syncthreads();
#pragma unroll
    for (int s = 0; s < 16; ++s) {
      float4 xv[4];
#pragma unroll
      for (int i = 0; i < 4; ++i) xv[i] = xs4[rg * 4 + i][s ^ (rg & 3)];
      const float4 wv0 = wt4[c0][s ^ cg];
      const float4 wv1 = wt4[c0 + 1][s ^ cg];
#pragma unroll
      for (int i = 0; i < 4; ++i) {
        acc[i][0] += xv[i].x * wv0.x + xv[i].y * wv0.y + xv[i].z * wv0.z + xv[i].w * wv0.w;
        acc[i][1] += xv[i].x * wv1.x + xv[i].y * wv1.y + xv[i].z * wv1.z + xv[i].w * wv1.w;
      }
    }
    __syncthreads();
  }
#pragma unroll
  for (int i = 0; i < 4; ++i) {
    const int row = row0 + rg * 4 + i;
    float2 o = make_float2(acc[i][0] + bias[c0], acc[i][1] + bias[c0 + 1]);
    *(float2*)(&pot[(size_t)row * KK + c0]) = o;
  }
}

// ---------------------------------------------------------------- scan2 -----
// grid 128 x 64. 1 batch per wave. Lane = jh*32 + k. j-split: half jh covers
// j = (k^p)^(jh*16), p=0..15. areg[p] built by xor16-seed + 4-level repl tree.
__global__ __launch_bounds__(64) void scan2(const float* __restrict__ pot,
                                            const int* __restrict__ lens,
                                            const float* __restrict__ trans,
                                            float* __restrict__ va,
                                            float* __restrict__ logZ,
                                            int* __restrict__ last) {
  const int lane = threadIdx.x;
  const int k = lane & 31;
  const int jh = lane >> 5;
  const bool is_lse = (blockIdx.x < 64);
  const int b = is_lse ? blockIdx.x : blockIdx.x - 64;
  const int len = lens[b];
  const float* pp = pot + (size_t)b * (TT * KK) + k;

  if (is_lse) {
    // ---------- linear-space logsumexp forward ----------
    float etrx[16];
#pragma unroll
    for (int p = 0; p < 16; ++p)
      etrx[p] = __expf(trans[((((k ^ p) ^ (jh << 4))) << 5) + k]);
    const float a0 = pp[0];
    const float M0 = wmax32(a0);
    float a = __expf(a0 - M0);
    float alog = M0;
    float ep[8], en[8];
#pragma unroll
    for (int i = 0; i < 8; ++i) ep[i] = __expf(pp[(size_t)(1 + i) * KK]);
    int rc = 0;
    for (int tb = 1; tb < len; tb += 8) {
#pragma unroll
      for (int i = 0; i < 8; ++i) en[i] = pp[(size_t)(tb + 8 + i) * KK];
#pragma unroll
      for (int i = 0; i < 8; ++i) {
        const int t = tb + i;
        if (t >= len) break;
        // replicate a over this half's j-subset
        const float sw = __shfl_xor(a, 16, 32);
        float areg[16];
        areg[0] = jh ? sw : a;
        areg[1] = __shfl_xor(areg[0], 1, 32);
#pragma unroll
        for (int p = 0; p < 2; ++p) areg[2 + p] = __shfl_xor(areg[p], 2, 32);
#pragma unroll
        for (int p = 0; p < 4; ++p) areg[4 + p] = __shfl_xor(areg[p], 4, 32);
#pragma unroll
        for (int p = 0; p < 8; ++p) areg[8 + p] = __shfl_xor(areg[p], 8, 32);
        float d0 = 0.f, d1 = 0.f, d2 = 0.f, d3 = 0.f;
#pragma unroll
        for (int p = 0; p < 4; ++p) {
          d0 += areg[4 * p + 0] * etrx[4 * p + 0];
          d1 += areg[4 * p + 1] * etrx[4 * p + 1];
          d2 += areg[4 * p + 2] * etrx[4 * p + 2];
          d3 += areg[4 * p + 3] * etrx[4 * p + 3];
        }
        float dot = (d0 + d1) + (d2 + d3);
        dot += __shfl_xor(dot, 32);          // combine halves (width 64)
        a = dot * ep[i];
        if (++rc == 4) {                     // renorm every 4 steps
          rc = 0;
          const float mx = wmax32(a);
          alog += __logf(mx);
          a *= (1.0f / mx);
        }
      }
#pragma unroll
      for (int i = 0; i < 8; ++i) ep[i] = __expf(en[i]);
    }
    const float ssum = wsum32(a);
    if (lane == 0) logZ[b] = alog + __logf(ssum);
  } else {
    // ---------- Viterbi max-plus forward ----------
    float trx[16];
#pragma unroll
    for (int p = 0; p < 16; ++p)
      trx[p] = trans[((((k ^ p) ^ (jh << 4))) << 5) + k];
    float a = pp[0];
    float* vap = va + (size_t)b * (TT * KK) + k;
    if (lane < 32) vap[0] = a;
    float pb[8], pn[8];
#pragma unroll
    for (int i = 0; i < 8; ++i) pb[i] = pp[(size_t)(1 + i) * KK];
    for (int tb = 1; tb < len; tb += 8) {
#pragma unroll
      for (int i = 0; i < 8; ++i) pn[i] = pp[(size_t)(tb + 8 + i) * KK];
#pragma unroll
      for (int i = 0; i < 8; ++i) {
        const int t = tb + i;
        if (t >= len) break;
        const float sw = __shfl_xor(a, 16, 32);
        float areg[16];
        areg[0] = jh ? sw : a;
        areg[1] = __shfl_xor(areg[0], 1, 32);
#pragma unroll
        for (int p = 0; p < 2; ++p) areg[2 + p] = __shfl_xor(areg[p], 2, 32);
#pragma unroll
        for (int p = 0; p < 4; ++p) areg[4 + p] = __shfl_xor(areg[p], 4, 32);
#pragma unroll
        for (int p = 0; p < 8; ++p) areg[8 + p] = __shfl_xor(areg[p], 8, 32);
        float s[16];
#pragma unroll
        for (int p = 0; p < 16; ++p) s[p] = areg[p] + trx[p];
        float m8[8];
#pragma unroll
        for (int p = 0; p < 8; ++p) m8[p] = fmaxf(s[2 * p], s[2 * p + 1]);
        float m4[4];
#pragma unroll
        for (int p = 0; p < 4; ++p) m4[p] = fmaxf(m8[2 * p], m8[2 * p + 1]);
        float m = fmaxf(fmaxf(m4[0], m4[1]), fmaxf(m4[2], m4[3]));
        m = fmaxf(m, __shfl_xor(m, 32));     // combine halves (width 64)
        a = m + pb[i];
        if (lane < 32) vap[(size_t)t * KK] = a;
      }
#pragma unroll
      for (int i = 0; i < 8; ++i) pb[i] = pn[i];
    }
    // argmax over k (first-index tiebreak), within half 0
    float v = a;
    int idx = k;
#pragma unroll
    for (int mm = 16; mm >= 1; mm >>= 1) {
      const float vo = __shfl_xor(v, mm, 32);
      const int io = __shfl_xor(idx, mm, 32);
      if (vo > v || (vo == v && io < idx)) { v = vo; idx = io; }
    }
    if (lane == 0) last[b] = idx;
  }
}

// ----------------------------------------------------------- bp extract -----
__global__ __launch_bounds__(256) void bp_extract(const float* __restrict__ va,
                                                  const float* __restrict__ trans,
                                                  unsigned char* __restrict__ bp) {
  const int b = blockIdx.x >> 3;
  const int tbase = (blockIdx.x & 7) * 64;
  const int k = threadIdx.x & 31;
  const int ts = threadIdx.x >> 5;
  float tr[32];
#pragma unroll
  for (int j = 0; j < 32; ++j) tr[j] = trans[j * KK + k];
#pragma unroll
  for (int it = 0; it < 8; ++it) {
    const int t = tbase + it * 8 + ts;
    if (t < 1) continue;
    const float* row = va + ((size_t)b * TT + (t - 1)) * KK;
    float best = row[0] + tr[0];
    int bi = 0;
#pragma unroll
    for (int j = 1; j < 32; ++j) {
      const float s = row[j] + tr[j];
      if (s > best) { best = s; bi = j; }
    }
    bp[((size_t)b * TT + t) * KK + k] = (unsigned char)bi;
  }
}

// ------------------------------------------------------------- backtrace ----
__global__ __launch_bounds__(256) void backtrace_kernel(
    const unsigned char* __restrict__ bp, const int* __restrict__ lens,
    const int* __restrict__ last, const float* __restrict__ pot,
    const int* __restrict__ y, const float* __restrict__ trans,
    const float* __restrict__ logZ, float* __restrict__ out) {
  __shared__ unsigned char Ls[32736];
  __shared__ unsigned char sA[512], sB[512];
  __shared__ float red[256];
  const int b = blockIdx.x, tid = threadIdx.x;
  const int len = lens[b];

  for (int i = tid; i < TT * KK; i += 256) {
    const int t = i >> 5, k = i & 31;
    Ls[i] = (t >= 1 && t < len) ? bp[((size_t)b * TT + t) * KK + k] : (unsigned char)k;
  }
  __syncthreads();

  int off_prev = 0, cnt = 512;
  for (int l = 1; l <= 9; ++l) {
    const int off = 32 * (1024 - (1024 >> l));
    const int n = cnt >> 1;
    for (int i = tid; i < n * 32; i += 256) {
      const int m = i >> 5, k = i & 31;
      const int inner = Ls[off_prev + (2 * m + 1) * 32 + k];
      Ls[off + i] = Ls[off_prev + (2 * m) * 32 + inner];
    }
    __syncthreads();
    off_prev = off;
    cnt = n;
  }

  if (tid == 0) sA[0] = (unsigned char)last[b];
  __syncthreads();

  unsigned char* cur = sA;
  unsigned char* nxt = sB;
  int c2 = 1;
  for (int l = 9; l >= 1; --l) {
    const int offm = 32 * (1024 - (1024 >> (l - 1)));
    for (int i = tid; i < c2; i += 256) {
      const unsigned char s = cur[i];
      nxt[2 * i + 1] = s;
      nxt[2 * i] = Ls[offm + (2 * i + 1) * 32 + s];
    }
    __syncthreads();
    unsigned char* tmp = cur; cur = nxt; nxt = tmp;
    c2 <<= 1;
  }

  for (int t = tid; t < TT; t += 256)
    out[NB + (size_t)b * TT + t] = (t < len) ? (float)cur[t] : 0.f;

  float acc = 0.f;
  for (int t = tid; t < TT; t += 256) {
    const int yt = y[b * TT + t];
    if (t < len) acc += pot[((size_t)b * TT + t) * KK + yt];
    if (t < len - 1) acc += trans[yt * KK + y[b * TT + t + 1]];
  }
  red[tid] = acc;
  __syncthreads();
  for (int s = 128; s >= 1; s >>= 1) {
    if (tid < s) red[tid] += red[tid + s];
    __syncthreads();
  }
  if (tid == 0) out[b] = red[0] - logZ[b];
}

// ------------------------------------------------------------------ launch --
extern "C" void kernel_launch(void* const* d_in, const int* in_sizes, int n_in,
                              void* d_out, int out_size, void* d_ws, size_t ws_size,
                              hipStream_t stream) {
  const float* x = (const float*)d_in[0];
  const int* y = (const int*)d_in[1];
  const int* lens = (const int*)d_in[2];
  const float* W = (const float*)d_in[3];
  const float* bias = (const float*)d_in[4];
  const float* trans = (const float*)d_in[5];
  float* out = (float*)d_out;
  char* ws = (char*)d_ws;
  float* pot = (float*)(ws + WS_POT);
  float* va = (float*)(ws + WS_VA);
  unsigned char* bp = (unsigned char*)(ws + WS_BP);
  float* logZ = (float*)(ws + WS_LOGZ);
  int* last = (int*)(ws + WS_LAST);

  gemm_pot<<<512, 256, 0, stream>>>(x, W, bias, pot);
  scan2<<<128, 64, 0, stream>>>(pot, lens, trans, va, logZ, last);
  bp_extract<<<512, 256, 0, stream>>>(va, trans, bp);
  backtrace_kernel<<<64, 256, 0, stream>>>(bp, lens, last, pot, y, trans, logZ, out);
}

// Round 5
// 153.842 us; speedup vs baseline: 17.5992x; 1.3266x over previous
//
#include <hip/hip_runtime.h>
#include <hip/hip_bf16.h>
#include <stdint.h>

// CRF entity layer: B=64, T=512, H=768, K=32
//   1) gemm_pot: pot[b][t][k] = x[b,t,:]·W[:,k] + b[k]
//   2) scan2:    blocks [0,64)  : linear-space LSE forward -> logZ[b]
//                blocks [64,128): Viterbi max-plus forward -> va, last[b]
//      1 batch/wave; j-split across halves; cross-lane via DPP + permlane swaps
//      (VALU latency) instead of ds_bpermute (~110cyc) — the r4 bottleneck.
//   3) bp_extract: bp[b][t][k] = argmax_j(va[t-1][j]+trans[j][k])
//   4) backtrace: log-depth composition scan -> preds; + seq score -> ll
//
// ws layout (bytes):
//   pot : 0         4MB (+4KB pad: prefetch overshoot to t<=526)
//   va  : 4198400   4MB (+4KB pad)
//   bp  : 8396800   1MB
//   logZ: 9445376   256B
//   last: 9445632   256B

#define TT 512
#define KK 32
#define HH 768
#define NB 64

#define WS_POT 0
#define WS_VA  4198400
#define WS_BP  8396800
#define WS_LOGZ 9445376
#define WS_LAST 9445632

// ---------------- cross-lane primitives (VALU-speed) ----------------
// DPP move: lane gets value from lane^mask (within 16-lane rows).
// ctrls: xor1 = quad_perm[1,0,3,2]=0xB1; xor2 = quad_perm[2,3,0,1]=0x4E;
//        xor7 = row_half_mirror=0x141;   xor8 = row_ror:8=0x128.
template <int CTRL>
__device__ __forceinline__ float dppx(float x) {
  return __int_as_float(__builtin_amdgcn_update_dpp(
      0, __float_as_int(x), CTRL, 0xF, 0xF, true));
}

typedef unsigned int uint2v __attribute__((ext_vector_type(2)));

#if __has_builtin(__builtin_amdgcn_permlane16_swap)
__device__ __forceinline__ float xor16f(float x) {
  const unsigned xu = __float_as_uint(x);
  const uint2v q = __builtin_amdgcn_permlane16_swap(xu, xu, false, false);
  return __uint_as_float(q.x ^ q.y ^ xu);   // direction-agnostic: x[lane^16]
}
#else
__device__ __forceinline__ float xor16f(float x) {   // ds_swizzle xor16 fallback
  return __int_as_float(__builtin_amdgcn_ds_swizzle(__float_as_int(x), 0x401F));
}
#endif

#if __has_builtin(__builtin_amdgcn_permlane32_swap)
__device__ __forceinline__ float xor32f(float x) {
  const unsigned xu = __float_as_uint(x);
  const uint2v q = __builtin_amdgcn_permlane32_swap(xu, xu, false, false);
  return __uint_as_float(q.x ^ q.y ^ xu);   // x[lane^32]
}
#else
__device__ __forceinline__ float xor32f(float x) { return __shfl_xor(x, 32, 64); }
#endif

// all-reduce over the 32 k-slots within each 32-lane half
__device__ __forceinline__ float redmax32(float v) {
  v = fmaxf(v, dppx<0xB1>(v));
  v = fmaxf(v, dppx<0x4E>(v));
  v = fmaxf(v, dppx<0x141>(v));
  v = fmaxf(v, dppx<0x128>(v));
  v = fmaxf(v, xor16f(v));
  return v;
}
__device__ __forceinline__ float redsum32(float v) {
  v += dppx<0xB1>(v);
  v += dppx<0x4E>(v);
  v += dppx<0x141>(v);
  v += dppx<0x128>(v);
  v += xor16f(v);
  return v;
}

// Gray-generator index map: G[m] = (m&1)*1 ^ (m&2?2:0) ^ (m&4?7:0) ^ (m&8?8:0)
__device__ __forceinline__ int gmap(int m) {
  return ((m & 1) ? 1 : 0) ^ ((m & 2) ? 2 : 0) ^ ((m & 4) ? 7 : 0) ^ ((m & 8) ? 8 : 0);
}

// replication tree: A[m] = seed_from_lane(k ^ G[m]); 15 v_mov_dpp, depth 4.
#define REPL_TREE(A)                                            \
  A[1] = dppx<0xB1>(A[0]);                                      \
  _Pragma("unroll") for (int p = 0; p < 2; ++p) A[2 + p] = dppx<0x4E>(A[p]);  \
  _Pragma("unroll") for (int p = 0; p < 4; ++p) A[4 + p] = dppx<0x141>(A[p]); \
  _Pragma("unroll") for (int p = 0; p < 8; ++p) A[8 + p] = dppx<0x128>(A[p]);

// ---------------------------------------------------------------- GEMM ------
__global__ __launch_bounds__(256) void gemm_pot(const float* __restrict__ x,
                                                const float* __restrict__ W,
                                                const float* __restrict__ bias,
                                                float* __restrict__ pot) {
  __shared__ float4 xs4[64][16];
  __shared__ float4 wt4[32][16];
  const int tid = threadIdx.x;
  const int row0 = blockIdx.x * 64;
  const int cg = tid & 15;
  const int rg = tid >> 4;
  const int c0 = cg * 2;
  float acc[4][2] = {{0.f, 0.f}, {0.f, 0.f}, {0.f, 0.f}, {0.f, 0.f}};

  for (int h0 = 0; h0 < HH; h0 += 64) {
#pragma unroll
    for (int p = 0; p < 4; ++p) {
      const int fi = tid + p * 256;
      const int r = fi >> 4, s = fi & 15;
      const float4 v = *(const float4*)(&x[(size_t)(row0 + r) * HH + h0 + s * 4]);
      xs4[r][s ^ ((r >> 2) & 3)] = v;
    }
    {
      const int c = tid & 31;
      const int hb = (tid >> 5) * 8;
      float* wf = (float*)(&wt4[0][0]);
#pragma unroll
      for (int i2 = 0; i2 < 8; ++i2) {
        const int hh = hb + i2;
        const int slot = (hh >> 2) ^ ((c >> 1) & 15);
        wf[c * 64 + slot * 4 + (hh & 3)] = W[(size_t)(h0 + hh) * KK + c];
      }
    }
    __syncthreads();
#pragma unroll
    for (int s = 0; s < 16; ++s) {
      float4 xv[4];
#pragma unroll
      for (int i = 0; i < 4; ++i) xv[i] = xs4[rg * 4 + i][s ^ (rg & 3)];
      const float4 wv0 = wt4[c0][s ^ cg];
      const float4 wv1 = wt4[c0 + 1][s ^ cg];
#pragma unroll
      for (int i = 0; i < 4; ++i) {
        acc[i][0] += xv[i].x * wv0.x + xv[i].y * wv0.y + xv[i].z * wv0.z + xv[i].w * wv0.w;
        acc[i][1] += xv[i].x * wv1.x + xv[i].y * wv1.y + xv[i].z * wv1.z + xv[i].w * wv1.w;
      }
    }
    __syncthreads();
  }
#pragma unroll
  for (int i = 0; i < 4; ++i) {
    const int row = row0 + rg * 4 + i;
    float2 o = make_float2(acc[i][0] + bias[c0], acc[i][1] + bias[c0 + 1]);
    *(float2*)(&pot[(size_t)row * KK + c0]) = o;
  }
}

// ---------------------------------------------------------------- scan2 -----
// grid 128 x 64. 1 batch per wave. lane = jh*32 + k. Half jh covers
// j = k ^ G[m] ^ (jh<<4), m=0..15. State a_k replicated in both halves.
__global__ __launch_bounds__(64) void scan2(const float* __restrict__ pot,
                                            const int* __restrict__ lens,
                                            const float* __restrict__ trans,
                                            float* __restrict__ va,
                                            float* __restrict__ logZ,
                                            int* __restrict__ last) {
  const int lane = threadIdx.x;
  const int k = lane & 31;
  const int jh = lane >> 5;
  const bool is_lse = (blockIdx.x < 64);
  const int b = is_lse ? blockIdx.x : blockIdx.x - 64;
  const int len = lens[b];
  const float* pp = pot + (size_t)b * (TT * KK) + k;

  if (is_lse) {
    // ---------- linear-space logsumexp forward ----------
    float etrx[16];
#pragma unroll
    for (int m = 0; m < 16; ++m)
      etrx[m] = __expf(trans[((k ^ gmap(m) ^ (jh << 4)) << 5) + k]);
    const float a0 = pp[0];
    const float M0 = redmax32(a0);
    float a = __expf(a0 - M0);
    float alog = M0;
    float ep[8], en[8];
#pragma unroll
    for (int i = 0; i < 8; ++i) ep[i] = __expf(pp[(size_t)(1 + i) * KK]);
    for (int tb = 1; tb < len; tb += 8) {
#pragma unroll
      for (int i = 0; i < 8; ++i) en[i] = pp[(size_t)(tb + 8 + i) * KK];
#pragma unroll
      for (int i = 0; i < 8; ++i) {
        const int t = tb + i;
        if (t >= len) break;
        float A[16];
        const float u16 = xor16f(a);
        A[0] = jh ? u16 : a;
        REPL_TREE(A)
        float d0 = 0.f, d1 = 0.f, d2 = 0.f, d3 = 0.f;
#pragma unroll
        for (int p = 0; p < 4; ++p) {
          d0 += A[4 * p + 0] * etrx[4 * p + 0];
          d1 += A[4 * p + 1] * etrx[4 * p + 1];
          d2 += A[4 * p + 2] * etrx[4 * p + 2];
          d3 += A[4 * p + 3] * etrx[4 * p + 3];
        }
        float part = (d0 + d1) + (d2 + d3);
        a = (part + xor32f(part)) * ep[i];
        if ((t & 3) == 0) {                   // renorm every 4 steps
          const float mx = redmax32(a);
          alog += __logf(mx);
          a *= (1.0f / mx);
        }
      }
#pragma unroll
      for (int i = 0; i < 8; ++i) ep[i] = __expf(en[i]);
    }
    const float ssum = redsum32(a);
    if (lane == 0) logZ[b] = alog + __logf(ssum);
  } else {
    // ---------- Viterbi max-plus forward ----------
    float trx[16];
#pragma unroll
    for (int m = 0; m < 16; ++m)
      trx[m] = trans[((k ^ gmap(m) ^ (jh << 4)) << 5) + k];
    float a = pp[0];
    float* vap = va + (size_t)b * (TT * KK) + k;
    if (lane < 32) vap[0] = a;
    float pb[8], pn[8];
#pragma unroll
    for (int i = 0; i < 8; ++i) pb[i] = pp[(size_t)(1 + i) * KK];
    for (int tb = 1; tb < len; tb += 8) {
#pragma unroll
      for (int i = 0; i < 8; ++i) pn[i] = pp[(size_t)(tb + 8 + i) * KK];
#pragma unroll
      for (int i = 0; i < 8; ++i) {
        const int t = tb + i;
        if (t >= len) break;
        float A[16];
        const float u16 = xor16f(a);
        A[0] = jh ? u16 : a;
        REPL_TREE(A)
        float s_[16];
#pragma unroll
        for (int m = 0; m < 16; ++m) s_[m] = A[m] + trx[m];
        const float m0 = fmaxf(fmaxf(s_[0], s_[1]), fmaxf(s_[2], s_[3]));
        const float m1 = fmaxf(fmaxf(s_[4], s_[5]), fmaxf(s_[6], s_[7]));
        const float m2 = fmaxf(fmaxf(s_[8], s_[9]), fmaxf(s_[10], s_[11]));
        const float m3 = fmaxf(fmaxf(s_[12], s_[13]), fmaxf(s_[14], s_[15]));
        const float part = fmaxf(fmaxf(m0, m1), fmaxf(m2, m3));
        a = fmaxf(part, xor32f(part)) + pb[i];
        if (lane < 32) vap[(size_t)t * KK] = a;
      }
#pragma unroll
      for (int i = 0; i < 8; ++i) pb[i] = pn[i];
    }
    // argmax over k (first-index tiebreak)
    float v = a;
    int idx = k;
#pragma unroll
    for (int mm = 16; mm >= 1; mm >>= 1) {
      const float vo = __shfl_xor(v, mm, 32);
      const int io = __shfl_xor(idx, mm, 32);
      if (vo > v || (vo == v && io < idx)) { v = vo; idx = io; }
    }
    if (lane == 0) last[b] = idx;
  }
}

// ----------------------------------------------------------- bp extract -----
__global__ __launch_bounds__(256) void bp_extract(const float* __restrict__ va,
                                                  const float* __restrict__ trans,
                                                  unsigned char* __restrict__ bp) {
  const int b = blockIdx.x >> 3;
  const int tbase = (blockIdx.x & 7) * 64;
  const int k = threadIdx.x & 31;
  const int ts = threadIdx.x >> 5;
  float tr[32];
#pragma unroll
  for (int j = 0; j < 32; ++j) tr[j] = trans[j * KK + k];
#pragma unroll
  for (int it = 0; it < 8; ++it) {
    const int t = tbase + it * 8 + ts;
    if (t < 1) continue;
    const float* row = va + ((size_t)b * TT + (t - 1)) * KK;
    float best = row[0] + tr[0];
    int bi = 0;
#pragma unroll
    for (int j = 1; j < 32; ++j) {
      const float s = row[j] + tr[j];
      if (s > best) { best = s; bi = j; }
    }
    bp[((size_t)b * TT + t) * KK + k] = (unsigned char)bi;
  }
}

// ------------------------------------------------------------- backtrace ----
__global__ __launch_bounds__(256) void backtrace_kernel(
    const unsigned char* __restrict__ bp, const int* __restrict__ lens,
    const int* __restrict__ last, const float* __restrict__ pot,
    const int* __restrict__ y, const float* __restrict__ trans,
    const float* __restrict__ logZ, float* __restrict__ out) {
  __shared__ unsigned char Ls[32736];
  __shared__ unsigned char sA[512], sB[512];
  __shared__ float red[256];
  const int b = blockIdx.x, tid = threadIdx.x;
  const int len = lens[b];

  for (int i = tid; i < TT * KK; i += 256) {
    const int t = i >> 5, k = i & 31;
    Ls[i] = (t >= 1 && t < len) ? bp[((size_t)b * TT + t) * KK + k] : (unsigned char)k;
  }
  __syncthreads();

  int off_prev = 0, cnt = 512;
  for (int l = 1; l <= 9; ++l) {
    const int off = 32 * (1024 - (1024 >> l));
    const int n = cnt >> 1;
    for (int i = tid; i < n * 32; i += 256) {
      const int m = i >> 5, k = i & 31;
      const int inner = Ls[off_prev + (2 * m + 1) * 32 + k];
      Ls[off + i] = Ls[off_prev + (2 * m) * 32 + inner];
    }
    __syncthreads();
    off_prev = off;
    cnt = n;
  }

  if (tid == 0) sA[0] = (unsigned char)last[b];
  __syncthreads();

  unsigned char* cur = sA;
  unsigned char* nxt = sB;
  int c2 = 1;
  for (int l = 9; l >= 1; --l) {
    const int offm = 32 * (1024 - (1024 >> (l - 1)));
    for (int i = tid; i < c2; i += 256) {
      const unsigned char s = cur[i];
      nxt[2 * i + 1] = s;
      nxt[2 * i] = Ls[offm + (2 * i + 1) * 32 + s];
    }
    __syncthreads();
    unsigned char* tmp = cur; cur = nxt; nxt = tmp;
    c2 <<= 1;
  }

  for (int t = tid; t < TT; t += 256)
    out[NB + (size_t)b * TT + t] = (t < len) ? (float)cur[t] : 0.f;

  float acc = 0.f;
  for (int t = tid; t < TT; t += 256) {
    const int yt = y[b * TT + t];
    if (t < len) acc += pot[((size_t)b * TT + t) * KK + yt];
    if (t < len - 1) acc += trans[yt * KK + y[b * TT + t + 1]];
  }
  red[tid] = acc;
  __syncthreads();
  for (int s = 128; s >= 1; s >>= 1) {
    if (tid < s) red[tid] += red[tid + s];
    __syncthreads();
  }
  if (tid == 0) out[b] = red[0] - logZ[b];
}

// ------------------------------------------------------------------ launch --
extern "C" void kernel_launch(void* const* d_in, const int* in_sizes, int n_in,
                              void* d_out, int out_size, void* d_ws, size_t ws_size,
                              hipStream_t stream) {
  const float* x = (const float*)d_in[0];
  const int* y = (const int*)d_in[1];
  const int* lens = (const int*)d_in[2];
  const float* W = (const float*)d_in[3];
  const float* bias = (const float*)d_in[4];
  const float* trans = (const float*)d_in[5];
  float* out = (float*)d_out;
  char* ws = (char*)d_ws;
  float* pot = (float*)(ws + WS_POT);
  float* va = (float*)(ws + WS_VA);
  unsigned char* bp = (unsigned char*)(ws + WS_BP);
  float* logZ = (float*)(ws + WS_LOGZ);
  int* last = (int*)(ws + WS_LAST);

  gemm_pot<<<512, 256, 0, stream>>>(x, W, bias, pot);
  scan2<<<128, 64, 0, stream>>>(pot, lens, trans, va, logZ, last);
  bp_extract<<<512, 256, 0, stream>>>(va, trans, bp);
  backtrace_kernel<<<64, 256, 0, stream>>>(bp, lens, last, pot, y, trans, logZ, out);
}